// Round 1
// baseline (797.905 us; speedup 1.0000x reference)
//
#include <hip/hip_runtime.h>

#define NY 17
#define NIN 72
#define NGRID 129
#define NMLP (NY * NIN)      // 1224
#define OUTROW (NGRID * NY)  // 2193
#define NMIR (NGRID - NIN)   // 57
#define TOTAL_F 0.078f
#define SPB 8                // samples per block in out_kernel
#define PTS_PER_BLK 8        // table points per block in build_kernel

__device__ __forceinline__ float sigmoidf(float z) {
    return 1.0f / (1.0f + __expf(-z));
}

// ---------------------------------------------------------------------------
// Kernel 1: mirror coefficients (57 entries). Faithful to the reference:
//   x_pos = TOTAL - xs[j];  near = (TOTAL - x_pos) < 0.02
//   near  -> col1=col2=clip(argmin|x_pos-xs|,0,71), w=1
//   else  -> col1=clip(searchsorted_right(xs,x_pos)-1,0,70), col2=col1+1,
//            w=(xs[col2]-x_pos)/(xs[col2]-xs[col1])
// ---------------------------------------------------------------------------
__global__ void coef_kernel(const float* __restrict__ xs,
                            int* __restrict__ c1, int* __restrict__ c2,
                            float* __restrict__ wgt) {
    int jj = threadIdx.x;
    if (jj >= NMIR) return;
    int j = NIN + jj;
    float x_pos = TOTAL_F - xs[j];
    bool near = (TOTAL_F - x_pos) < 0.02f;

    // argmin |x_pos - xs[i]| (first minimum, like jnp.argmin)
    int amin = 0;
    float best = fabsf(x_pos - xs[0]);
    for (int i = 1; i < NGRID; ++i) {
        float d = fabsf(x_pos - xs[i]);
        if (d < best) { best = d; amin = i; }
    }
    int col_near = min(max(amin, 0), NIN - 1);

    // searchsorted side='right': count of xs[i] <= x_pos
    int cnt = 0;
    for (int i = 0; i < NGRID; ++i) cnt += (xs[i] <= x_pos) ? 1 : 0;
    int col1 = min(max(cnt - 1, 0), NIN - 2);
    int col2 = col1 + 1;
    float w = (xs[col2] - x_pos) / (xs[col2] - xs[col1]);

    if (near) { col1 = col_near; col2 = col_near; w = 1.0f; }
    c1[jj] = col1;
    c2[jj] = col2;
    wgt[jj] = w;
}

// ---------------------------------------------------------------------------
// Kernel 2: build the lookup table  table[ti][m] = sigmoid(h2(x_ti) . W3[:,m] + b3[m])
// for x_ti = xmin + ti*dx, m = 0..1223. Each block handles PTS_PER_BLK points
// so W3 columns are loaded once and reused across the 8 points.
// ---------------------------------------------------------------------------
__global__ void build_kernel(const float* __restrict__ W1, const float* __restrict__ b1,
                             const float* __restrict__ W2, const float* __restrict__ b2,
                             const float* __restrict__ W3, const float* __restrict__ b3,
                             float* __restrict__ table,
                             int tabx, float xmin, float dx) {
    __shared__ float h2s[PTS_PER_BLK][104];  // 100 used, padded
    int p0 = blockIdx.x * PTS_PER_BLK;
    int tid = threadIdx.x;

    if (tid < 100) {
        for (int p = 0; p < PTS_PER_BLK; ++p) {
            int ti = p0 + p;
            if (ti > tabx - 1) ti = tabx - 1;
            float x = xmin + dx * (float)ti;
            float acc = b2[tid];
            #pragma unroll
            for (int jL = 0; jL < 10; ++jL) {
                float h1 = sigmoidf(x * W1[jL] + b1[jL]);
                acc = fmaf(h1, W2[jL * 100 + tid], acc);
            }
            h2s[p][tid] = sigmoidf(acc);
        }
    }
    __syncthreads();

    for (int col = tid; col < NMLP; col += blockDim.x) {
        float acc[PTS_PER_BLK];
        float bv = b3[col];
        #pragma unroll
        for (int p = 0; p < PTS_PER_BLK; ++p) acc[p] = bv;
        for (int k = 0; k < 100; ++k) {
            float wv = W3[k * NMLP + col];
            #pragma unroll
            for (int p = 0; p < PTS_PER_BLK; ++p) acc[p] = fmaf(h2s[p][k], wv, acc[p]);
        }
        #pragma unroll
        for (int p = 0; p < PTS_PER_BLK; ++p) {
            int ti = p0 + p;
            if (ti < tabx) table[(size_t)ti * NMLP + col] = sigmoidf(acc[p]);
        }
    }
}

// ---------------------------------------------------------------------------
// Kernel 3: per-sample output via table interpolation.
// out[b, r]: r < 1224 -> lerp(table[i0][r], table[i0+1][r])
//            r >= 1224 -> w*xg(col1) + (1-w)*xg(col2), xg via same lerp.
// ---------------------------------------------------------------------------
__global__ void out_kernel(const float* __restrict__ x, const float* __restrict__ table,
                           const int* __restrict__ c1, const int* __restrict__ c2,
                           const float* __restrict__ wgt, float* __restrict__ out,
                           int Btot, int tabx, float xmin, float inv_dx) {
    int base_s = blockIdx.x * SPB;
    const int span = SPB * OUTROW;
    size_t base_e = (size_t)base_s * OUTROW;

    for (int e = threadIdx.x; e < span; e += blockDim.x) {
        int bloc = e / OUTROW;
        int b = base_s + bloc;
        if (b >= Btot) break;
        int r = e - bloc * OUTROW;

        float xv = x[b];
        float t = (xv - xmin) * inv_dx;
        t = fminf(fmaxf(t, 0.0f), (float)(tabx - 1));
        int i0 = (int)t;
        if (i0 > tabx - 2) i0 = tabx - 2;
        float f = t - (float)i0;

        const float* __restrict__ r0 = table + (size_t)i0 * NMLP;
        const float* __restrict__ r1 = r0 + NMLP;

        float v;
        if (r < NMLP) {
            float a = r0[r];
            float bb = r1[r];
            v = fmaf(f, bb - a, a);
        } else {
            int rr = r - NMLP;
            int jj = rr / NY;
            int y = rr - jj * NY;
            int m1 = c1[jj] * NY + y;
            int m2 = c2[jj] * NY + y;
            float w = wgt[jj];
            float a1 = r0[m1];
            float v1 = fmaf(f, r1[m1] - a1, a1);
            float a2 = r0[m2];
            float v2 = fmaf(f, r1[m2] - a2, a2);
            v = fmaf(w, v1 - v2, v2);  // w*v1 + (1-w)*v2
        }
        out[base_e + e] = v;
    }
}

extern "C" void kernel_launch(void* const* d_in, const int* in_sizes, int n_in,
                              void* d_out, int out_size, void* d_ws, size_t ws_size,
                              hipStream_t stream) {
    const float* x  = (const float*)d_in[0];
    const float* W1 = (const float*)d_in[1];
    const float* b1 = (const float*)d_in[2];
    const float* W2 = (const float*)d_in[3];
    const float* b2 = (const float*)d_in[4];
    const float* W3 = (const float*)d_in[5];
    const float* b3 = (const float*)d_in[6];
    const float* xs = (const float*)d_in[7];
    float* out = (float*)d_out;
    int B = in_sizes[0];  // 65536 (x is [B,1])

    // Workspace layout: [table: tabx*1224 floats][c1:57 int][c2:57 int][w:57 float]
    int tabx = 1024;
    size_t extra = 3 * 64 * sizeof(int) + 256;
    while (tabx > 64 && (size_t)tabx * NMLP * sizeof(float) + extra > ws_size) tabx >>= 1;

    float* table = (float*)d_ws;
    char* p = (char*)d_ws + (size_t)tabx * NMLP * sizeof(float);
    int* c1 = (int*)p;
    int* c2 = c1 + 64;
    float* wgt = (float*)(c2 + 64);

    const float xmin = -6.0f, xmax = 6.0f;
    float dx = (xmax - xmin) / (float)(tabx - 1);

    coef_kernel<<<1, 64, 0, stream>>>(xs, c1, c2, wgt);
    build_kernel<<<(tabx + PTS_PER_BLK - 1) / PTS_PER_BLK, 256, 0, stream>>>(
        W1, b1, W2, b2, W3, b3, table, tabx, xmin, dx);
    out_kernel<<<(B + SPB - 1) / SPB, 256, 0, stream>>>(
        x, table, c1, c2, wgt, out, B, tabx, xmin, 1.0f / dx);
}

// Round 2
// 640.400 us; speedup vs baseline: 1.2459x; 1.2459x over previous
//
#include <hip/hip_runtime.h>

#define NY 17
#define NIN 72
#define NGRID 129
#define NMLP (NY * NIN)      // 1224
#define OUTROW (NGRID * NY)  // 2193
#define NMIR (NGRID - NIN)   // 57
#define TOTAL_F 0.078f
#define PTS_PER_BLK 8        // table points per block in build_kernel
#define COL_TILES 4          // column tiles in build_kernel (1224/4 = 306)

__device__ __forceinline__ float sigmoidf(float z) {
    return 1.0f / (1.0f + __expf(-z));
}

// ---------------------------------------------------------------------------
// Kernel 1: mirror coefficients (57 entries). Faithful to the reference.
// ---------------------------------------------------------------------------
__global__ void coef_kernel(const float* __restrict__ xs,
                            int* __restrict__ c1, int* __restrict__ c2,
                            float* __restrict__ wgt) {
    int jj = threadIdx.x;
    if (jj >= NMIR) return;
    int j = NIN + jj;
    float x_pos = TOTAL_F - xs[j];
    bool near = (TOTAL_F - x_pos) < 0.02f;

    int amin = 0;
    float best = fabsf(x_pos - xs[0]);
    for (int i = 1; i < NGRID; ++i) {
        float d = fabsf(x_pos - xs[i]);
        if (d < best) { best = d; amin = i; }
    }
    int col_near = min(max(amin, 0), NIN - 1);

    int cnt = 0;
    for (int i = 0; i < NGRID; ++i) cnt += (xs[i] <= x_pos) ? 1 : 0;
    int col1 = min(max(cnt - 1, 0), NIN - 2);
    int col2 = col1 + 1;
    float w = (xs[col2] - x_pos) / (xs[col2] - xs[col1]);

    if (near) { col1 = col_near; col2 = col_near; w = 1.0f; }
    c1[jj] = col1;
    c2[jj] = col2;
    wgt[jj] = w;
}

// ---------------------------------------------------------------------------
// Kernel 2: build lookup table table[ti][m] = sigmoid(h2(x_ti).W3[:,m]+b3[m]).
// grid (tabx/8, 4): 8 table points x 306-column tile per block. Each block
// reads only its own W3 column tile, so total W3 traffic is unchanged while
// block count rises 128 -> 512 for occupancy.
// ---------------------------------------------------------------------------
__global__ void build_kernel(const float* __restrict__ W1, const float* __restrict__ b1,
                             const float* __restrict__ W2, const float* __restrict__ b2,
                             const float* __restrict__ W3, const float* __restrict__ b3,
                             float* __restrict__ table,
                             int tabx, float xmin, float dx) {
    __shared__ float h2s[PTS_PER_BLK][104];  // 100 used, padded
    int p0 = blockIdx.x * PTS_PER_BLK;
    int c0 = blockIdx.y * (NMLP / COL_TILES);  // 306-wide tile
    int cend = c0 + (NMLP / COL_TILES);
    int tid = threadIdx.x;

    if (tid < 100) {
        for (int p = 0; p < PTS_PER_BLK; ++p) {
            int ti = p0 + p;
            if (ti > tabx - 1) ti = tabx - 1;
            float x = xmin + dx * (float)ti;
            float acc = b2[tid];
            #pragma unroll
            for (int jL = 0; jL < 10; ++jL) {
                float h1 = sigmoidf(x * W1[jL] + b1[jL]);
                acc = fmaf(h1, W2[jL * 100 + tid], acc);
            }
            h2s[p][tid] = sigmoidf(acc);
        }
    }
    __syncthreads();

    for (int col = c0 + tid; col < cend; col += blockDim.x) {
        float acc[PTS_PER_BLK];
        float bv = b3[col];
        #pragma unroll
        for (int p = 0; p < PTS_PER_BLK; ++p) acc[p] = bv;
        for (int k = 0; k < 100; ++k) {
            float wv = W3[k * NMLP + col];
            #pragma unroll
            for (int p = 0; p < PTS_PER_BLK; ++p) acc[p] = fmaf(h2s[p][k], wv, acc[p]);
        }
        #pragma unroll
        for (int p = 0; p < PTS_PER_BLK; ++p) {
            int ti = p0 + p;
            if (ti < tabx) table[(size_t)ti * NMLP + col] = sigmoidf(acc[p]);
        }
    }
}

// ---------------------------------------------------------------------------
// Kernel 3: one block per 2 samples. Stage pre-lerped MLP row into LDS once
// per sample (contiguous 9792 B global read: rows i0,i0+1 are adjacent),
// then emit 4386 floats as 2193 coalesced float2 stores (8 B aligned since
// the 2-sample window is 17544 B = 8*2193 B).
// ---------------------------------------------------------------------------
__global__ __launch_bounds__(256) void out_kernel(
        const float* __restrict__ x, const float* __restrict__ table,
        const int* __restrict__ c1, const int* __restrict__ c2,
        const float* __restrict__ wgt, float* __restrict__ out,
        int Btot, int tabx, float xmin, float inv_dx) {
    __shared__ float L[2][NMLP];
    __shared__ int sc1[NMIR];
    __shared__ int sc2[NMIR];
    __shared__ float sw[NMIR];

    int tid = threadIdx.x;
    if (tid < NMIR) {
        sc1[tid] = c1[tid];
        sc2[tid] = c2[tid];
        sw[tid]  = wgt[tid];
    }

    int b0 = blockIdx.x * 2;
    if (b0 >= Btot) return;
    int nsmp = (b0 + 1 < Btot) ? 2 : 1;

    for (int s = 0; s < nsmp; ++s) {
        float xv = x[b0 + s];
        float t = (xv - xmin) * inv_dx;
        t = fminf(fmaxf(t, 0.0f), (float)(tabx - 1));
        int i0 = (int)t;
        if (i0 > tabx - 2) i0 = tabx - 2;
        float f = t - (float)i0;
        const float* __restrict__ r0 = table + (size_t)i0 * NMLP;
        for (int r = tid; r < NMLP; r += 256) {
            float a  = r0[r];
            float bb = r0[r + NMLP];
            L[s][r] = fmaf(f, bb - a, a);
        }
    }
    __syncthreads();

    int nelem = nsmp * OUTROW;                 // 4386 (or 2193 tail)
    size_t base = (size_t)b0 * OUTROW;
    float2* __restrict__ out2 = (float2*)(out + base);  // 8B-aligned

    for (int q = tid; 2 * q < nelem; q += 256) {
        int e0 = 2 * q;
        int e1 = e0 + 1;

        // element e0
        int s0 = (e0 >= OUTROW) ? 1 : 0;
        int r  = e0 - s0 * OUTROW;
        float vx;
        if (r < NMLP) {
            vx = L[s0][r];
        } else {
            int rr = r - NMLP;
            int jj = rr / NY;
            int y  = rr - jj * NY;
            float w  = sw[jj];
            float v1 = L[s0][sc1[jj] * NY + y];
            float v2 = L[s0][sc2[jj] * NY + y];
            vx = fmaf(w, v1 - v2, v2);
        }

        if (e1 < nelem) {
            int s1 = (e1 >= OUTROW) ? 1 : 0;
            int r1 = e1 - s1 * OUTROW;
            float vy;
            if (r1 < NMLP) {
                vy = L[s1][r1];
            } else {
                int rr = r1 - NMLP;
                int jj = rr / NY;
                int y  = rr - jj * NY;
                float w  = sw[jj];
                float v1 = L[s1][sc1[jj] * NY + y];
                float v2 = L[s1][sc2[jj] * NY + y];
                vy = fmaf(w, v1 - v2, v2);
            }
            float2 v; v.x = vx; v.y = vy;
            out2[q] = v;
        } else {
            out[base + e0] = vx;  // odd tail (B even in practice)
        }
    }
}

extern "C" void kernel_launch(void* const* d_in, const int* in_sizes, int n_in,
                              void* d_out, int out_size, void* d_ws, size_t ws_size,
                              hipStream_t stream) {
    const float* x  = (const float*)d_in[0];
    const float* W1 = (const float*)d_in[1];
    const float* b1 = (const float*)d_in[2];
    const float* W2 = (const float*)d_in[3];
    const float* b2 = (const float*)d_in[4];
    const float* W3 = (const float*)d_in[5];
    const float* b3 = (const float*)d_in[6];
    const float* xs = (const float*)d_in[7];
    float* out = (float*)d_out;
    int B = in_sizes[0];  // 65536 (x is [B,1])

    int tabx = 1024;
    size_t extra = 3 * 64 * sizeof(int) + 256;
    while (tabx > 64 && (size_t)tabx * NMLP * sizeof(float) + extra > ws_size) tabx >>= 1;

    float* table = (float*)d_ws;
    char* p = (char*)d_ws + (size_t)tabx * NMLP * sizeof(float);
    int* c1 = (int*)p;
    int* c2 = c1 + 64;
    float* wgt = (float*)(c2 + 64);

    const float xmin = -6.0f, xmax = 6.0f;
    float dx = (xmax - xmin) / (float)(tabx - 1);

    coef_kernel<<<1, 64, 0, stream>>>(xs, c1, c2, wgt);
    dim3 bgrid((tabx + PTS_PER_BLK - 1) / PTS_PER_BLK, COL_TILES);
    build_kernel<<<bgrid, 256, 0, stream>>>(W1, b1, W2, b2, W3, b3, table, tabx, xmin, dx);
    out_kernel<<<(B + 1) / 2, 256, 0, stream>>>(
        x, table, c1, c2, wgt, out, B, tabx, xmin, 1.0f / dx);
}